// Round 8
// baseline (224.053 us; speedup 1.0000x reference)
//
#include <hip/hip_runtime.h>
#include <hip/hip_bf16.h>

#define NEG_SLOPE 0.2f
#define EPSV 1e-8f
#define BCAP 3072    // slots per 128-node bucket (mean 2046 for E=1.6M; ~23 sigma margin)

typedef float f32x4 __attribute__((ext_vector_type(4)));
typedef short bf16x8 __attribute__((ext_vector_type(8)));      // 8 bf16 (4 VGPRs) MFMA frag
typedef unsigned short us8 __attribute__((ext_vector_type(8)));

static __device__ __forceinline__ unsigned short ftobf16(float f) {
    __hip_bfloat16 b = __float2bfloat16(f);
    return *(unsigned short*)&b;
}
static __device__ __forceinline__ float leaky_exp(float v) {
    v = fmaxf(v, NEG_SLOPE * v);
    return __expf(v);   // softmax shift-invariant; |v| bounded small
}

// ---------------------------------------------------------------------------
// Kernel 1 (FUSED): role-split by blockIdx.
//   gemm role   : h = x @ W^T via bf16 MFMA + fused alpha epilogue (identical
//                 math to the round-3/6/7 version that passed).
//   scatter role: coarse bucket partition (bucket = dst>>7, 128 nodes/bucket,
//                 NBK<=1024). 256 thr x 16 edges (static unroll, no scratch),
//                 LDS histogram, ONE global reservation per bucket per block
//                 (epb=4096 halves the per-address atomic chain vs r7),
//                 packed payload (local_dst<<23 | src; src < 2^23).
// ---------------------------------------------------------------------------
__global__ __launch_bounds__(256, 2) void k_gemm_scatter(
        const float* __restrict__ x, const float* __restrict__ W,
        const float* __restrict__ a, unsigned short* __restrict__ h_bf,
        float* __restrict__ asrc, float* __restrict__ adst,
        const int* __restrict__ ei, int* __restrict__ relcur,
        unsigned* __restrict__ ebuf, int E, int N, int GB, int SB) {
    __shared__ unsigned short xs[128 * 128];   // gemm: x tile / h tile; scatter: counters
    __shared__ unsigned short ws[128 * 128];   // gemm: W tile
    __shared__ float sa[256];                  // gemm: a (4,64)
    int tid = threadIdx.x;
    int bid = blockIdx.x;

    // ---- role assignment: interleave gemm/scatter over the first 2*min ----
    int M = min(GB, SB);
    bool isGemm; int myIdx;
    if (bid < 2 * M) { isGemm = ((bid & 1) == 0); myIdx = bid >> 1; }
    else { isGemm = (GB > SB); myIdx = bid - M; }

    if (!isGemm) {
        // ================= scatter role =================
        int* hist  = (int*)xs;          // 1024 ints
        int* wcur  = hist + 1024;       // 1024 ints
        int* bslot = wcur + 1024;       // 1024 ints
        int lo = myIdx * 4096;
        int hi = min(E, lo + 4096);
#pragma unroll
        for (int j = 0; j < 4; ++j) {
            hist[tid + 256 * j] = 0;
            wcur[tid + 256 * j] = 0;
        }
        __syncthreads();
        int sreg[16], dreg[16];
#pragma unroll
        for (int k = 0; k < 16; k++) {
            int e = lo + tid + 256 * k;
            if (e < hi) {
                sreg[k] = ei[e];
                dreg[k] = ei[E + e];
                atomicAdd(&hist[dreg[k] >> 7], 1);
            }
        }
        __syncthreads();
#pragma unroll
        for (int j = 0; j < 4; ++j) {
            int bb = tid + 256 * j;
            int c = hist[bb];
            int r = c ? atomicAdd(&relcur[bb], c) : 0;
            bslot[bb] = bb * BCAP + r;
        }
        __syncthreads();
#pragma unroll
        for (int k = 0; k < 16; k++) {
            int e = lo + tid + 256 * k;
            if (e < hi) {
                int s = sreg[k];
                int d = dreg[k];
                int b = d >> 7;
                int off = atomicAdd(&wcur[b], 1);
                int slot = bslot[b] + off;
                if (slot < (b + 1) * BCAP)    // overflow guard (never fires)
                    ebuf[slot] = ((unsigned)(d & 127) << 23) | (unsigned)s;
            }
        }
        return;
    }

    // ================= gemm role =================
    int nb = myIdx * 128;
    sa[tid] = a[tid];

    // ---- stage x (bf16) and W (bf16) into LDS, swizzle: k ^ ((row&7)<<3) ----
#pragma unroll
    for (int it = 0; it < 16; ++it) {
        int f = tid + 256 * it;        // 4096 float4-chunks
        int row = f >> 5;              // 0..127
        int k0 = (f & 31) << 2;        // 0..124, step 4
        int sw = row * 128 + (k0 ^ ((row & 7) << 3));
        int n = nb + row; if (n >= N) n = N - 1;
        float4 v = *(const float4*)(x + (size_t)n * 128 + k0);
        ushort4 o;
        o.x = ftobf16(v.x); o.y = ftobf16(v.y);
        o.z = ftobf16(v.z); o.w = ftobf16(v.w);
        *(ushort4*)&xs[sw] = o;
        float4 wv = *(const float4*)(W + (size_t)row * 128 + k0);
        ushort4 ow;
        ow.x = ftobf16(wv.x); ow.y = ftobf16(wv.y);
        ow.z = ftobf16(wv.z); ow.w = ftobf16(wv.w);
        *(ushort4*)&ws[sw] = ow;
    }
    __syncthreads();

    int w  = tid >> 6;    // wave: rows [w*32, w*32+32)
    int l  = tid & 63;
    int lr = l & 15;      // A-row (j) / B-col (n) within tile
    int lg = l >> 4;      // k-group; also D row-group

    f32x4 acc[2][8];      // [node-tile][j-tile]
    {
        f32x4 zz = {0.f, 0.f, 0.f, 0.f};
#pragma unroll
        for (int nt = 0; nt < 2; ++nt)
#pragma unroll
            for (int jt = 0; jt < 8; ++jt)
                acc[nt][jt] = zz;
    }

#pragma unroll
    for (int ks = 0; ks < 4; ++ks) {
        int kofs = ks * 32 + lg * 8;
        bf16x8 xf[2];
#pragma unroll
        for (int nt = 0; nt < 2; ++nt) {
            int row = w * 32 + nt * 16 + lr;
            xf[nt] = *(const bf16x8*)&xs[row * 128 + (kofs ^ ((row & 7) << 3))];
        }
#pragma unroll
        for (int jt = 0; jt < 8; ++jt) {
            int j = jt * 16 + lr;
            bf16x8 wf = *(const bf16x8*)&ws[j * 128 + (kofs ^ ((j & 7) << 3))];
#pragma unroll
            for (int nt = 0; nt < 2; ++nt)
                acc[nt][jt] = __builtin_amdgcn_mfma_f32_16x16x32_bf16(
                    wf, xf[nt], acc[nt][jt], 0, 0, 0);
        }
    }

    // ---- fused alpha epilogue from fp32 accumulators ----
#pragma unroll
    for (int g = 0; g < 4; ++g) {
        f32x4 as0 = *(const f32x4*)&sa[g * 64 +      lg * 4];
        f32x4 as1 = *(const f32x4*)&sa[g * 64 + 16 + lg * 4];
        f32x4 ad0 = *(const f32x4*)&sa[g * 64 + 32 + lg * 4];
        f32x4 ad1 = *(const f32x4*)&sa[g * 64 + 48 + lg * 4];
#pragma unroll
        for (int nt = 0; nt < 2; ++nt) {
            float ps = 0.f, pd = 0.f;
#pragma unroll
            for (int r = 0; r < 4; ++r) {
                ps += acc[nt][2 * g][r] * as0[r] + acc[nt][2 * g + 1][r] * as1[r];
                pd += acc[nt][2 * g][r] * ad0[r] + acc[nt][2 * g + 1][r] * ad1[r];
            }
            ps += __shfl_xor(ps, 16); pd += __shfl_xor(pd, 16);
            ps += __shfl_xor(ps, 32); pd += __shfl_xor(pd, 32);
            if (lg == 0) {
                int n = nb + w * 32 + nt * 16 + lr;
                if (n < N) {
                    asrc[(size_t)n * 4 + g] = ps;
                    adst[(size_t)n * 4 + g] = pd;
                }
            }
        }
    }

    // ---- h repack through LDS (reuse xs) -> coalesced 16B stores ----
    __syncthreads();   // everyone done reading xs/ws
#pragma unroll
    for (int nt = 0; nt < 2; ++nt) {
        int row = w * 32 + nt * 16 + lr;
        int m = (row & 7) << 3;
#pragma unroll
        for (int jt = 0; jt < 8; ++jt) {
            int j0 = jt * 16 + lg * 4;
            ushort4 o;
            o.x = ftobf16(acc[nt][jt][0]);
            o.y = ftobf16(acc[nt][jt][1]);
            o.z = ftobf16(acc[nt][jt][2]);
            o.w = ftobf16(acc[nt][jt][3]);
            *(ushort4*)&xs[row * 128 + (j0 ^ m)] = o;
        }
    }
    __syncthreads();
#pragma unroll
    for (int it = 0; it < 8; ++it) {
        int f = tid + 256 * it;        // 2048 8-ushort chunks
        int row = f >> 4;
        int c8 = (f & 15) << 3;
        int n = nb + row;
        if (n < N) {
            us8 v = *(const us8*)&xs[row * 128 + (c8 ^ ((row & 7) << 3))];
            *(us8*)(h_bf + (size_t)n * 128 + c8) = v;
        }
    }
}

// ---------------------------------------------------------------------------
// Kernel 2 (MERGED build+agg): one 512-thread block per 128-node bucket.
// Phase 1: bucket CSR built entirely in LDS (histogram w/ rank capture, 6
//   static reg slots, 128-wide scan, direct placement) — csr_src/row_ptr
//   never touch global memory.
// Phase 2: aggregate the bucket's 128 nodes. 8 waves x 4 nodes/round x 4
//   rounds; 16-lane group per node, lane owns 8 feats (dwordx4 h-gather =
//   4 edges/instr). Edge ids are LDS-broadcast reads from csr_lds (se
//   staging deleted); exp-weight staging sw stays double-buffered with the
//   T14 issue-early/write-late pipeline + depth-2 rotated gather prefetch.
// ---------------------------------------------------------------------------
__global__ __launch_bounds__(512) void k_bagg(
        const int* __restrict__ relcur, const unsigned* __restrict__ ebuf,
        const float* __restrict__ asrc, const float* __restrict__ adst,
        const unsigned short* __restrict__ h_bf,
        float* __restrict__ out, int N) {
    __shared__ int   csr_lds[BCAP];   // bucket CSR: src ids ordered by node
    __shared__ int   offx[128];       // per-node start within csr_lds
    __shared__ int   dg[128];         // per-node degree
    __shared__ int   hist[128];
    __shared__ int   smB[128];
    __shared__ float swb[8][2][272];  // [wave][buf][group*68 + 4*slot + head]
    int b = blockIdx.x;
    int t = threadIdx.x;
    int cnt = min(relcur[b], BCAP);
    const unsigned* ep = ebuf + (size_t)b * BCAP;

    // ---- phase 1a: histogram with rank capture (single ebuf read) ----
    if (t < 128) hist[t] = 0;
    __syncthreads();
    unsigned pay[6]; int rnk[6];
#pragma unroll
    for (int k = 0; k < 6; ++k) {
        int i = t + 512 * k;
        if (i < cnt) {
            unsigned p = ep[i];
            pay[k] = p;
            rnk[k] = atomicAdd(&hist[p >> 23], 1);
        } else {
            pay[k] = 0u;
            rnk[k] = -1;
        }
    }
    __syncthreads();

    // ---- phase 1b: 128-wide scan -> per-node offsets ----
    if (t < 128) { int s = hist[t]; dg[t] = s; smB[t] = s; }
    __syncthreads();
    for (int off = 1; off < 128; off <<= 1) {
        int u = (t >= off && t < 128) ? smB[t - off] : 0;
        __syncthreads();
        if (t < 128) smB[t] += u;
        __syncthreads();
    }
    if (t < 128) offx[t] = smB[t] - dg[t];
    __syncthreads();

    // ---- phase 1c: direct placement into LDS CSR (no atomics) ----
#pragma unroll
    for (int k = 0; k < 6; ++k) {
        if (rnk[k] >= 0) {
            unsigned p = pay[k];
            csr_lds[offx[p >> 23] + rnk[k]] = (int)(p & 0x7FFFFFu);
        }
    }
    __syncthreads();

    // ---- phase 2: aggregate 128 nodes (8 waves x 4 nodes x 4 rounds) ----
    int w  = t >> 6;
    int l  = t & 63;
    int gg = l >> 4;      // group (node) within wave
    int m  = l & 15;      // lane within group; owns feats 8m..8m+7
    int hh = m >> 2;      // head of those feats
    const unsigned short* hp = h_bf + 8 * m;

#define ACC8(U, WT) do { \
        union { unsigned u; float f; } q; \
        q.u = (U).x << 16;         acc[0] += (WT) * q.f; \
        q.u = (U).x & 0xFFFF0000u; acc[1] += (WT) * q.f; \
        q.u = (U).y << 16;         acc[2] += (WT) * q.f; \
        q.u = (U).y & 0xFFFF0000u; acc[3] += (WT) * q.f; \
        q.u = (U).z << 16;         acc[4] += (WT) * q.f; \
        q.u = (U).z & 0xFFFF0000u; acc[5] += (WT) * q.f; \
        q.u = (U).w << 16;         acc[6] += (WT) * q.f; \
        q.u = (U).w & 0xFFFF0000u; acc[7] += (WT) * q.f; \
    } while (0)

    for (int r = 0; r < 4; ++r) {
        int nl = r * 32 + w * 4 + gg;     // node-local 0..127
        int n = (b << 7) + nl;
        bool valid = (n < N);
        int nc = valid ? n : (N - 1);
        int lo  = offx[nl];
        int deg = dg[nl];
        float4 dv = *(const float4*)(adst + 4 * (size_t)nc);

        int md = deg;
        md = max(md, __shfl_xor(md, 16));
        md = max(md, __shfl_xor(md, 32));
        int nch = (md + 15) >> 4;

        float acc[8] = {};
        float asum = 0.f;

        // stage chunk 0 into buffer 0
        if (m < deg) {
            int s = csr_lds[lo + m];
            float4 sv = *(const float4*)(asrc + 4 * (size_t)s);
            float4 wv;
            wv.x = leaky_exp(sv.x + dv.x);
            wv.y = leaky_exp(sv.y + dv.y);
            wv.z = leaky_exp(sv.z + dv.z);
            wv.w = leaky_exp(sv.w + dv.w);
            *(float4*)&swb[w][0][68 * gg + 4 * m] = wv;
        }
        __builtin_amdgcn_wave_barrier();

        for (int c = 0; c < nch; ++c) {
            int cb = c & 1;
            // ---- issue next chunk's asrc gather early (write later) ----
            int sN = 0; float4 svN; bool haveN = false;
            {
                int eN = (c + 1) * 16 + m;
                if (c + 1 < nch && eN < deg) {
                    sN = csr_lds[lo + eN];
                    svN = *(const float4*)(asrc + 4 * (size_t)sN);
                    haveN = true;
                }
            }
            __builtin_amdgcn_wave_barrier();
            // ---- consume chunk c (depth-2 rotated prefetch) ----
            int base16 = c * 16;
            int ccnt = min(deg - base16, 16);
            const int*   idp = &csr_lds[lo + base16];
            const float* swp = &swb[w][cb][68 * gg];
            int i = 0;
            uint4 u0, u1;
            if (ccnt >= 2) {
                u0 = *(const uint4*)(hp + (size_t)idp[0] * 128);
                u1 = *(const uint4*)(hp + (size_t)idp[1] * 128);
            }
            for (; i + 4 <= ccnt; i += 2) {
                uint4 t0 = *(const uint4*)(hp + (size_t)idp[i + 2] * 128);
                uint4 t1 = *(const uint4*)(hp + (size_t)idp[i + 3] * 128);
                float w0 = swp[4 * i + hh];
                float w1 = swp[4 * i + 4 + hh];
                ACC8(u0, w0);
                ACC8(u1, w1);
                asum += w0 + w1;
                u0 = t0; u1 = t1;
            }
            if (i + 2 <= ccnt) {
                float w0 = swp[4 * i + hh];
                float w1 = swp[4 * i + 4 + hh];
                ACC8(u0, w0);
                ACC8(u1, w1);
                asum += w0 + w1;
                i += 2;
            }
            for (; i < ccnt; ++i) {
                float w0 = swp[4 * i + hh];
                uint4 uu = *(const uint4*)(hp + (size_t)idp[i] * 128);
                ACC8(uu, w0);
                asum += w0;
            }
            // ---- write next chunk's staging to the other buffer ----
            if (haveN) {
                float4 wv;
                wv.x = leaky_exp(svN.x + dv.x);
                wv.y = leaky_exp(svN.y + dv.y);
                wv.z = leaky_exp(svN.z + dv.z);
                wv.w = leaky_exp(svN.w + dv.w);
                *(float4*)&swb[w][cb ^ 1][68 * gg + 4 * m] = wv;
            }
            __builtin_amdgcn_wave_barrier();
        }

        if (valid) {
            float inv = 1.f / (asum + EPSV);
            float4 o0, o1;
            o0.x = acc[0] * inv; o0.y = acc[1] * inv;
            o0.z = acc[2] * inv; o0.w = acc[3] * inv;
            o1.x = acc[4] * inv; o1.y = acc[5] * inv;
            o1.z = acc[6] * inv; o1.w = acc[7] * inv;
            *(float4*)(out + (size_t)n * 128 + 8 * m) = o0;
            *(float4*)(out + (size_t)n * 128 + 8 * m + 4) = o1;
        }
    }
#undef ACC8
}

extern "C" void kernel_launch(void* const* d_in, const int* in_sizes, int n_in,
                              void* d_out, int out_size, void* d_ws, size_t ws_size,
                              hipStream_t stream) {
    const float* x = (const float*)d_in[0];   // fp32 (N,128)
    const float* W = (const float*)d_in[1];   // fp32 (128,128)
    const float* a = (const float*)d_in[2];   // fp32 (4,64)
    const int* ei = (const int*)d_in[3];      // int32 (2,E)
    float* out = (float*)d_out;               // fp32 (N,128)

    int N = in_sizes[0] / 128;
    int E = in_sizes[3] / 2;
    int NBK = (N + 127) >> 7;                 // 128-node buckets (<=1024 for N<=131072)

    char* wsb = (char*)d_ws;
    size_t off = 0;
    auto alloc = [&](size_t bytes) -> void* {
        void* p = wsb + off;
        off += (bytes + 255) / 256 * 256;
        return p;
    };
    unsigned short* h_bf = (unsigned short*)alloc((size_t)N * 128 * 2);   // 25.6 MB
    float* asrc = (float*)alloc((size_t)N * 4 * 4);
    float* adst = (float*)alloc((size_t)N * 4 * 4);
    int* relcur = (int*)alloc(1024 * 4);
    unsigned* ebuf = (unsigned*)alloc((size_t)NBK * BCAP * 4);            // ~9.6 MB

    hipMemsetAsync(relcur, 0, 1024 * 4, stream);

    int GB = (N + 127) / 128;                 // gemm blocks
    int SB = (E + 4095) / 4096;               // scatter blocks
    k_gemm_scatter<<<GB + SB, 256, 0, stream>>>(x, W, a, h_bf, asrc, adst,
                                                ei, relcur, ebuf, E, N, GB, SB);
    k_bagg<<<NBK, 512, 0, stream>>>(relcur, ebuf, asrc, adst, h_bf, out, N);
}

// Round 9
// 220.306 us; speedup vs baseline: 1.0170x; 1.0170x over previous
//
#include <hip/hip_runtime.h>
#include <hip/hip_bf16.h>

#define NEG_SLOPE 0.2f
#define EPSV 1e-8f
#define BCAP 5632    // slots per 256-node bucket (mean 4082 for E=1.6M; ~24 sigma margin)

typedef float f32x4 __attribute__((ext_vector_type(4)));
typedef short bf16x8 __attribute__((ext_vector_type(8)));      // 8 bf16 (4 VGPRs) MFMA frag
typedef unsigned short us8 __attribute__((ext_vector_type(8)));

static __device__ __forceinline__ unsigned short ftobf16(float f) {
    __hip_bfloat16 b = __float2bfloat16(f);
    return *(unsigned short*)&b;
}
static __device__ __forceinline__ float leaky_exp(float v) {
    v = fmaxf(v, NEG_SLOPE * v);
    return __expf(v);   // softmax shift-invariant; |v| bounded small
}

// ---------------------------------------------------------------------------
// Kernel 1 (FUSED): role-split by blockIdx. Identical to round 7 (212 µs run).
// ---------------------------------------------------------------------------
__global__ __launch_bounds__(256, 2) void k_gemm_scatter(
        const float* __restrict__ x, const float* __restrict__ W,
        const float* __restrict__ a, unsigned short* __restrict__ h_bf,
        float* __restrict__ asrc, float* __restrict__ adst,
        const int* __restrict__ ei, int* __restrict__ relcur,
        unsigned* __restrict__ ebuf, int E, int N, int GB, int SB) {
    __shared__ unsigned short xs[128 * 128];   // gemm: x tile / h tile; scatter: counters
    __shared__ unsigned short ws[128 * 128];   // gemm: W tile
    __shared__ float sa[256];                  // gemm: a (4,64)
    int tid = threadIdx.x;
    int bid = blockIdx.x;

    int M = min(GB, SB);
    bool isGemm; int myIdx;
    if (bid < 2 * M) { isGemm = ((bid & 1) == 0); myIdx = bid >> 1; }
    else { isGemm = (GB > SB); myIdx = bid - M; }

    if (!isGemm) {
        // ================= scatter role =================
        int* hist  = (int*)xs;          // 512 ints
        int* wcur  = hist + 512;        // 512 ints
        int* bslot = wcur + 512;        // 512 ints
        int lo = myIdx * 2048;
        int hi = min(E, lo + 2048);
        hist[tid] = 0; hist[tid + 256] = 0;
        wcur[tid] = 0; wcur[tid + 256] = 0;
        __syncthreads();
        int sreg[8], dreg[8];
#pragma unroll
        for (int k = 0; k < 8; k++) {
            int e = lo + tid + 256 * k;
            if (e < hi) {
                sreg[k] = ei[e];
                dreg[k] = ei[E + e];
                atomicAdd(&hist[dreg[k] >> 8], 1);
            }
        }
        __syncthreads();
        int c0 = hist[tid], c1 = hist[tid + 256];
        int r0 = c0 ? atomicAdd(&relcur[tid], c0) : 0;
        int r1 = c1 ? atomicAdd(&relcur[tid + 256], c1) : 0;
        bslot[tid]       = tid * BCAP + r0;
        bslot[tid + 256] = (tid + 256) * BCAP + r1;
        __syncthreads();
#pragma unroll
        for (int k = 0; k < 8; k++) {
            int e = lo + tid + 256 * k;
            if (e < hi) {
                int s = sreg[k];
                int d = dreg[k];
                int b = d >> 8;
                int off = atomicAdd(&wcur[b], 1);
                int slot = bslot[b] + off;
                if (slot < (b + 1) * BCAP)    // overflow guard (never fires)
                    ebuf[slot] = ((unsigned)(d & 255) << 23) | (unsigned)s;
            }
        }
        return;
    }

    // ================= gemm role =================
    int nb = myIdx * 128;
    sa[tid] = a[tid];

#pragma unroll
    for (int it = 0; it < 16; ++it) {
        int f = tid + 256 * it;        // 4096 float4-chunks
        int row = f >> 5;              // 0..127
        int k0 = (f & 31) << 2;        // 0..124, step 4
        int sw = row * 128 + (k0 ^ ((row & 7) << 3));
        int n = nb + row; if (n >= N) n = N - 1;
        float4 v = *(const float4*)(x + (size_t)n * 128 + k0);
        ushort4 o;
        o.x = ftobf16(v.x); o.y = ftobf16(v.y);
        o.z = ftobf16(v.z); o.w = ftobf16(v.w);
        *(ushort4*)&xs[sw] = o;
        float4 wv = *(const float4*)(W + (size_t)row * 128 + k0);
        ushort4 ow;
        ow.x = ftobf16(wv.x); ow.y = ftobf16(wv.y);
        ow.z = ftobf16(wv.z); ow.w = ftobf16(wv.w);
        *(ushort4*)&ws[sw] = ow;
    }
    __syncthreads();

    int w  = tid >> 6;    // wave: rows [w*32, w*32+32)
    int l  = tid & 63;
    int lr = l & 15;      // A-row (j) / B-col (n) within tile
    int lg = l >> 4;      // k-group; also D row-group

    f32x4 acc[2][8];      // [node-tile][j-tile]
    {
        f32x4 zz = {0.f, 0.f, 0.f, 0.f};
#pragma unroll
        for (int nt = 0; nt < 2; ++nt)
#pragma unroll
            for (int jt = 0; jt < 8; ++jt)
                acc[nt][jt] = zz;
    }

#pragma unroll
    for (int ks = 0; ks < 4; ++ks) {
        int kofs = ks * 32 + lg * 8;
        bf16x8 xf[2];
#pragma unroll
        for (int nt = 0; nt < 2; ++nt) {
            int row = w * 32 + nt * 16 + lr;
            xf[nt] = *(const bf16x8*)&xs[row * 128 + (kofs ^ ((row & 7) << 3))];
        }
#pragma unroll
        for (int jt = 0; jt < 8; ++jt) {
            int j = jt * 16 + lr;
            bf16x8 wf = *(const bf16x8*)&ws[j * 128 + (kofs ^ ((j & 7) << 3))];
#pragma unroll
            for (int nt = 0; nt < 2; ++nt)
                acc[nt][jt] = __builtin_amdgcn_mfma_f32_16x16x32_bf16(
                    wf, xf[nt], acc[nt][jt], 0, 0, 0);
        }
    }

    // ---- fused alpha epilogue from fp32 accumulators ----
#pragma unroll
    for (int g = 0; g < 4; ++g) {
        f32x4 as0 = *(const f32x4*)&sa[g * 64 +      lg * 4];
        f32x4 as1 = *(const f32x4*)&sa[g * 64 + 16 + lg * 4];
        f32x4 ad0 = *(const f32x4*)&sa[g * 64 + 32 + lg * 4];
        f32x4 ad1 = *(const f32x4*)&sa[g * 64 + 48 + lg * 4];
#pragma unroll
        for (int nt = 0; nt < 2; ++nt) {
            float ps = 0.f, pd = 0.f;
#pragma unroll
            for (int r = 0; r < 4; ++r) {
                ps += acc[nt][2 * g][r] * as0[r] + acc[nt][2 * g + 1][r] * as1[r];
                pd += acc[nt][2 * g][r] * ad0[r] + acc[nt][2 * g + 1][r] * ad1[r];
            }
            ps += __shfl_xor(ps, 16); pd += __shfl_xor(pd, 16);
            ps += __shfl_xor(ps, 32); pd += __shfl_xor(pd, 32);
            if (lg == 0) {
                int n = nb + w * 32 + nt * 16 + lr;
                if (n < N) {
                    asrc[(size_t)n * 4 + g] = ps;
                    adst[(size_t)n * 4 + g] = pd;
                }
            }
        }
    }

    // ---- h repack through LDS (reuse xs) -> coalesced 16B stores ----
    __syncthreads();
#pragma unroll
    for (int nt = 0; nt < 2; ++nt) {
        int row = w * 32 + nt * 16 + lr;
        int m = (row & 7) << 3;
#pragma unroll
        for (int jt = 0; jt < 8; ++jt) {
            int j0 = jt * 16 + lg * 4;
            ushort4 o;
            o.x = ftobf16(acc[nt][jt][0]);
            o.y = ftobf16(acc[nt][jt][1]);
            o.z = ftobf16(acc[nt][jt][2]);
            o.w = ftobf16(acc[nt][jt][3]);
            *(ushort4*)&xs[row * 128 + (j0 ^ m)] = o;
        }
    }
    __syncthreads();
#pragma unroll
    for (int it = 0; it < 8; ++it) {
        int f = tid + 256 * it;        // 2048 8-ushort chunks
        int row = f >> 4;
        int c8 = (f & 15) << 3;
        int n = nb + row;
        if (n < N) {
            us8 v = *(const us8*)&xs[row * 128 + (c8 ^ ((row & 7) << 3))];
            *(us8*)(h_bf + (size_t)n * 128 + c8) = v;
        }
    }
}

// ---------------------------------------------------------------------------
// Kernel 2: per-bucket CSR build, single-pass w/ rank capture. Identical to
// round 7 (212 µs run).
// ---------------------------------------------------------------------------
__global__ __launch_bounds__(512) void k_build(const int* __restrict__ relcur,
        const unsigned* __restrict__ ebuf,
        int* __restrict__ row_ptr, int* __restrict__ csr_src,
        int NBK, int N, int E) {
    __shared__ int smA[512];    // bucket-count scan
    __shared__ int hist[256];   // counts -> exclusive offsets (reused)
    __shared__ int smB[256];
    int b = blockIdx.x;
    int t = threadIdx.x;

    smA[t] = (t < NBK) ? min(relcur[t], BCAP) : 0;
    __syncthreads();
    for (int off = 1; off < 512; off <<= 1) {
        int u = (t >= off) ? smA[t - off] : 0;
        __syncthreads();
        smA[t] += u;
        __syncthreads();
    }
    int cnt  = min(relcur[b], BCAP);
    int base = smA[b] - cnt;
    if (b == 0 && t == 0) row_ptr[N] = E;

    int d0 = b << 8;
    const unsigned* ep = ebuf + (size_t)b * BCAP;

    if (t < 256) hist[t] = 0;
    __syncthreads();
    unsigned pay[11]; int rnk[11];
#pragma unroll
    for (int k = 0; k < 11; ++k) {
        int i = t + 512 * k;
        if (i < cnt) {
            unsigned p = ep[i];
            pay[k] = p;
            rnk[k] = atomicAdd(&hist[p >> 23], 1);
        } else {
            pay[k] = 0u;
            rnk[k] = -1;
        }
    }
    __syncthreads();

    int s = (t < 256) ? hist[t] : 0;
    if (t < 256) smB[t] = s;
    __syncthreads();
    for (int off = 1; off < 256; off <<= 1) {
        int u = (t >= off && t < 256) ? smB[t - off] : 0;
        __syncthreads();
        if (t < 256) smB[t] += u;
        __syncthreads();
    }
    if (t < 256) {
        int ex = smB[t] - s;
        hist[t] = ex;                 // reuse hist as exclusive per-node offsets
        int node = d0 + t;
        if (node < N) row_ptr[node] = base + ex;
    }
    __syncthreads();

#pragma unroll
    for (int k = 0; k < 11; ++k) {
        if (rnk[k] >= 0) {
            unsigned p = pay[k];
            csr_src[base + hist[p >> 23] + rnk[k]] = (int)(p & 0x7FFFFFu);
        }
    }
}

// ---------------------------------------------------------------------------
// Kernel 3: aggregate, HALF-FEATURE pass (fh = 0: heads 0-1, fh = 1: heads
// 2-3). 8 lanes per node (lane owns 8 feats of the 64-wide half), 8 nodes
// per wave, 32 nodes per block. Per pass the cacheable h working set is
// 12.8 MB (vs 25.6) -> higher per-XCD L2 hit rate on the gather. Same
// double-buffered T14 issue-early/write-late pipeline + depth-2 rotated
// gather prefetch as round 7; weights staged as float2/edge.
// ---------------------------------------------------------------------------
__global__ __launch_bounds__(256) void k_agg(
        const int* __restrict__ row_ptr, const int* __restrict__ csr_src,
        const float* __restrict__ asrc, const float* __restrict__ adst,
        const unsigned short* __restrict__ h_bf,
        float* __restrict__ out, int N, int fh) {
    __shared__ int   se[4][2][8 * 17];    // [wave][buf][group*17 + slot]
    __shared__ float sw[4][2][8 * 34];    // [wave][buf][group*34 + 2*slot + head]
    int tid = threadIdx.x;
    int w  = tid >> 6;
    int l  = tid & 63;
    int gg = l >> 3;      // group (node) within wave, 0..7
    int m  = l & 7;       // lane within group; owns feats fh*64 + 8m .. +8
    int hh = m >> 2;      // head within half (0..1)

    int n = blockIdx.x * 32 + w * 8 + gg;
    bool valid = (n < N);
    int nc = valid ? n : (N - 1);
    int lo  = row_ptr[nc];
    int deg = row_ptr[nc + 1] - lo;
    float2 dv = *(const float2*)(adst + 4 * (size_t)nc + 2 * fh);

    int md = deg;
    md = max(md, __shfl_xor(md, 8));
    md = max(md, __shfl_xor(md, 16));
    md = max(md, __shfl_xor(md, 32));
    int nch = (md + 15) >> 4;

    float acc[8] = {};
    float asum = 0.f;
    const unsigned short* hp = h_bf + 64 * fh + 8 * m;   // per-lane feature base

#define ACC8(U, WT) do { \
        union { unsigned u; float f; } q; \
        q.u = (U).x << 16;         acc[0] += (WT) * q.f; \
        q.u = (U).x & 0xFFFF0000u; acc[1] += (WT) * q.f; \
        q.u = (U).y << 16;         acc[2] += (WT) * q.f; \
        q.u = (U).y & 0xFFFF0000u; acc[3] += (WT) * q.f; \
        q.u = (U).z << 16;         acc[4] += (WT) * q.f; \
        q.u = (U).z & 0xFFFF0000u; acc[5] += (WT) * q.f; \
        q.u = (U).w << 16;         acc[6] += (WT) * q.f; \
        q.u = (U).w & 0xFFFF0000u; acc[7] += (WT) * q.f; \
    } while (0)

    // stage chunk 0 into buffer 0 (each lane stages edges m and m+8)
    {
#pragma unroll
        for (int half = 0; half < 2; ++half) {
            int e = m + 8 * half;
            if (e < deg) {
                int s = csr_src[lo + e];
                se[w][0][17 * gg + e] = s;
                float2 sv = *(const float2*)(asrc + 4 * (size_t)s + 2 * fh);
                float2 wv;
                wv.x = leaky_exp(sv.x + dv.x);
                wv.y = leaky_exp(sv.y + dv.y);
                *(float2*)&sw[w][0][34 * gg + 2 * e] = wv;
            }
        }
    }

    for (int c = 0; c < nch; ++c) {
        int cb = c & 1;
        // ---- issue next chunk's global loads into registers (write later) ----
        int sN1 = 0, sN2 = 0; float2 svN1, svN2;
        bool haveN1 = false, haveN2 = false;
        {
            int eb = (c + 1) * 16;
            if (c + 1 < nch) {
                int e1 = eb + m, e2 = eb + m + 8;
                if (e1 < deg) {
                    sN1 = csr_src[lo + e1];
                    svN1 = *(const float2*)(asrc + 4 * (size_t)sN1 + 2 * fh);
                    haveN1 = true;
                }
                if (e2 < deg) {
                    sN2 = csr_src[lo + e2];
                    svN2 = *(const float2*)(asrc + 4 * (size_t)sN2 + 2 * fh);
                    haveN2 = true;
                }
            }
        }
        __builtin_amdgcn_wave_barrier();   // keep issue above consume; fence LDS order
        // ---- consume chunk c (depth-2 rotated prefetch) ----
        int base16 = c * 16;
        int cnt = min(deg - base16, 16);
        const int*   sep = &se[w][cb][17 * gg];
        const float* swp = &sw[w][cb][34 * gg];
        int i = 0;
        uint4 u0, u1;
        if (cnt >= 2) {
            u0 = *(const uint4*)(hp + (size_t)sep[0] * 128);
            u1 = *(const uint4*)(hp + (size_t)sep[1] * 128);
        }
        for (; i + 4 <= cnt; i += 2) {
            uint4 t0 = *(const uint4*)(hp + (size_t)sep[i + 2] * 128);
            uint4 t1 = *(const uint4*)(hp + (size_t)sep[i + 3] * 128);
            float w0 = swp[2 * i + hh];
            float w1 = swp[2 * i + 2 + hh];
            ACC8(u0, w0);
            ACC8(u1, w1);
            asum += w0 + w1;
            u0 = t0; u1 = t1;
        }
        if (i + 2 <= cnt) {
            float w0 = swp[2 * i + hh];
            float w1 = swp[2 * i + 2 + hh];
            ACC8(u0, w0);
            ACC8(u1, w1);
            asum += w0 + w1;
            i += 2;
        }
        for (; i < cnt; ++i) {
            int s0 = sep[i];
            float w0 = swp[2 * i + hh];
            uint4 uu = *(const uint4*)(hp + (size_t)s0 * 128);
            ACC8(uu, w0);
            asum += w0;
        }
        // ---- write next chunk's staging to the other buffer ----
        if (haveN1) {
            se[w][cb ^ 1][17 * gg + m] = sN1;
            float2 wv;
            wv.x = leaky_exp(svN1.x + dv.x);
            wv.y = leaky_exp(svN1.y + dv.y);
            *(float2*)&sw[w][cb ^ 1][34 * gg + 2 * m] = wv;
        }
        if (haveN2) {
            se[w][cb ^ 1][17 * gg + m + 8] = sN2;
            float2 wv;
            wv.x = leaky_exp(svN2.x + dv.x);
            wv.y = leaky_exp(svN2.y + dv.y);
            *(float2*)&sw[w][cb ^ 1][34 * gg + 2 * m + 16] = wv;
        }
        __builtin_amdgcn_wave_barrier();   // stage writes ordered before next consume
    }
#undef ACC8

    if (valid) {
        float inv = 1.f / (asum + EPSV);
        float4 o0, o1;
        o0.x = acc[0] * inv; o0.y = acc[1] * inv;
        o0.z = acc[2] * inv; o0.w = acc[3] * inv;
        o1.x = acc[4] * inv; o1.y = acc[5] * inv;
        o1.z = acc[6] * inv; o1.w = acc[7] * inv;
        float* op = out + (size_t)n * 128 + 64 * fh + 8 * m;
        *(float4*)op = o0;
        *(float4*)(op + 4) = o1;
    }
}

extern "C" void kernel_launch(void* const* d_in, const int* in_sizes, int n_in,
                              void* d_out, int out_size, void* d_ws, size_t ws_size,
                              hipStream_t stream) {
    const float* x = (const float*)d_in[0];   // fp32 (N,128)
    const float* W = (const float*)d_in[1];   // fp32 (128,128)
    const float* a = (const float*)d_in[2];   // fp32 (4,64)
    const int* ei = (const int*)d_in[3];      // int32 (2,E)
    float* out = (float*)d_out;               // fp32 (N,128)

    int N = in_sizes[0] / 128;
    int E = in_sizes[3] / 2;
    int NBK = (N + 255) >> 8;                 // 256-node buckets (<=512 for N<=131072)

    char* wsb = (char*)d_ws;
    size_t off = 0;
    auto alloc = [&](size_t bytes) -> void* {
        void* p = wsb + off;
        off += (bytes + 255) / 256 * 256;
        return p;
    };
    unsigned short* h_bf = (unsigned short*)alloc((size_t)N * 128 * 2);   // 25.6 MB
    float* asrc = (float*)alloc((size_t)N * 4 * 4);
    float* adst = (float*)alloc((size_t)N * 4 * 4);
    int* row_ptr = (int*)alloc((size_t)(N + 1) * 4);
    int* relcur = (int*)alloc(512 * 4);
    unsigned* ebuf = (unsigned*)alloc((size_t)NBK * BCAP * 4);            // ~8.8 MB
    int* csr_src = (int*)alloc((size_t)E * 4);

    hipMemsetAsync(relcur, 0, 512 * 4, stream);

    int GB = (N + 127) / 128;                 // gemm blocks
    int SB = (E + 2047) / 2048;               // scatter blocks
    k_gemm_scatter<<<GB + SB, 256, 0, stream>>>(x, W, a, h_bf, asrc, adst,
                                                ei, relcur, ebuf, E, N, GB, SB);
    k_build<<<NBK, 512, 0, stream>>>(relcur, ebuf, row_ptr, csr_src, NBK, N, E);
    int AGB = (N + 31) / 32;
    k_agg<<<AGB, 256, 0, stream>>>(row_ptr, csr_src, asrc, adst, h_bf, out, N, 0);
    k_agg<<<AGB, 256, 0, stream>>>(row_ptr, csr_src, asrc, adst, h_bf, out, N, 1);
}